// Round 1
// baseline (306.212 us; speedup 1.0000x reference)
//
#include <hip/hip_runtime.h>

typedef float v4f __attribute__((ext_vector_type(4)));
typedef short v8s __attribute__((ext_vector_type(8)));
typedef short v4s __attribute__((ext_vector_type(4)));

__device__ __forceinline__ unsigned short f2bf(float x){
    unsigned u = __float_as_uint(x);
    u += 0x7FFFu + ((u >> 16) & 1u);
    return (unsigned short)(u >> 16);
}
__device__ __forceinline__ float bf2f(unsigned short h){
    return __uint_as_float(((unsigned)h) << 16);
}

// ---------------- prep kernels ----------------
// W_node[d][h] = sum_c K[d][c]*ak[h][c] ; W_neigh[d][h] = sum_c K[d][c]*ak[h][128+c]
__global__ __launch_bounds__(256) void prep_a(const float* __restrict__ kern,
        const float* __restrict__ ak, float* __restrict__ wn, float* __restrict__ wg){
    int d = threadIdx.x;
    float an[8], ag[8];
    #pragma unroll
    for (int h=0;h<8;h++){ an[h]=0.f; ag[h]=0.f; }
    for (int c=0;c<128;c++){
        float kv = kern[d*128+c];
        #pragma unroll
        for (int h=0;h<8;h++){
            an[h] = fmaf(kv, ak[h*256+c], an[h]);
            ag[h] = fmaf(kv, ak[h*256+128+c], ag[h]);
        }
    }
    #pragma unroll
    for (int h=0;h<8;h++){ wn[d*8+h]=an[h]; wg[d*8+h]=ag[h]; }
}

// pack B = [kernel | W_neigh | 0pad] (256 x 144) into MFMA B-fragment order, bf16
// frag(kk,cc): lane l elem j = B[kk*32+(l>>4)*8+j][cc*16+(l&15)]
__global__ __launch_bounds__(256) void prep_b(const float* __restrict__ kern,
        const float* __restrict__ wg, unsigned short* __restrict__ packB){
    int tid = blockIdx.x*256 + threadIdx.x;   // 4096 threads
    for (int r=0;r<9;r++){
        int e = tid + r*4096;                  // < 36864
        int j = e & 7; int rest = e >> 3;
        int l = rest & 63; rest >>= 6;
        int cc = rest % 9; int kk = rest / 9;
        int d = kk*32 + (l>>4)*8 + j;
        int c = cc*16 + (l&15);
        float v;
        if (cc < 8) v = kern[d*128 + c];
        else { int h = c - 128; v = (h < 8) ? wg[d*8+h] : 0.0f; }
        packB[e] = f2bf(v);
    }
}

// node_score[b][h] = targets[b] . W_node[:,h]
__global__ __launch_bounds__(256) void prep_c(const float* __restrict__ targ,
        const float* __restrict__ wn, float* __restrict__ ns){
    int tid = blockIdx.x*256 + threadIdx.x;   // 4096
    for (int r=0;r<8;r++){
        int e = tid + r*4096;                  // 32768 = b*8+h
        int b = e >> 3, h = e & 7;
        float acc = 0.f;
        for (int d=0; d<256; d++) acc = fmaf(targ[b*256+d], wn[d*8+h], acc);
        ns[e] = acc;
    }
}

// pack sem_kernel (1024 x 128) into MFMA B-fragment order, bf16
__global__ __launch_bounds__(256) void prep_d(const float* __restrict__ semk,
        unsigned short* __restrict__ pack2){
    int tid = blockIdx.x*256 + threadIdx.x;   // 8192
    for (int r=0;r<16;r++){
        int e = tid + r*8192;                  // 131072
        int j = e & 7; int rest = e >> 3;
        int l = rest & 63; rest >>= 6;
        int cc = rest & 7; rest >>= 3;
        int kk = rest & 7; int kc = rest >> 3;
        int k = kc*256 + kk*32 + (l>>4)*8 + j;
        int a = cc*16 + (l&15);
        pack2[e] = f2bf(semk[k*128 + a]);
    }
}

// ---------------- phase 1: fused neigh GEMM + scores + softmax + z ----------------
// block = (g, 2 consecutive b).  M=64 rows (2b x 32n), Bmat = 256 x 144 (9 cc-tiles).
__global__ __launch_bounds__(256) void phase1(const float* __restrict__ ctx,
        const unsigned short* __restrict__ packB, const float* __restrict__ ns,
        const float* __restrict__ bias, float* __restrict__ zf){
    __shared__ __align__(16) unsigned short aT[64*256];    // 32 KB, xor-swizzled bf16
    __shared__ __align__(16) unsigned short outT[64*146];  // 18.7 KB bf16 (neigh+scores)
    __shared__ float cf[2*32*8];                           // coef [b][n][h], 2 KB

    int t = threadIdx.x;
    int bid = blockIdx.x;          // 6144 = 3 * 2048
    int g  = bid >> 11;
    int b0 = (bid & 2047) * 2;
    const float* cbase = ctx + (size_t)(g*4096 + b0) * 8192;

    // stage ctx (64 rows x 256 d) -> bf16 LDS with xor swizzle
    #pragma unroll
    for (int i=0;i<16;i++){
        int fi = (i*256 + t)*4;
        v4f v = *(const v4f*)(cbase + fi);
        int row = fi >> 8, d = fi & 255;
        v4s h;
        h[0]=(short)f2bf(v[0]); h[1]=(short)f2bf(v[1]); h[2]=(short)f2bf(v[2]); h[3]=(short)f2bf(v[3]);
        int byte = row*512 + ((d*2) ^ ((row&7)<<4));
        *(v4s*)((char*)aT + byte) = h;
    }
    __syncthreads();

    int w = t >> 6, lane = t & 63;
    int ncc = (w==0) ? 3 : 2;
    int ccl[3] = {w, w+4, 8};
    v4f acc[4][3];
    #pragma unroll
    for (int m=0;m<4;m++)
        #pragma unroll
        for (int i=0;i<3;i++) acc[m][i] = (v4f){0.f,0.f,0.f,0.f};

    for (int kk=0;kk<8;kk++){
        v8s bfr[3];
        #pragma unroll
        for (int i=0;i<3;i++)
            if (i < ncc)
                bfr[i] = *(const v8s*)(packB + (((kk*9 + ccl[i])*64 + lane) << 3));
        v8s afr[4];
        #pragma unroll
        for (int m=0;m<4;m++){
            int row = m*16 + (lane&15);
            int d0  = kk*32 + (lane>>4)*8;
            int byte = row*512 + ((d0*2) ^ ((row&7)<<4));
            afr[m] = *(const v8s*)((const char*)aT + byte);
        }
        #pragma unroll
        for (int m=0;m<4;m++)
            #pragma unroll
            for (int i=0;i<3;i++)
                if (i < ncc)
                    acc[m][i] = __builtin_amdgcn_mfma_f32_16x16x32_bf16(afr[m], bfr[i], acc[m][i], 0,0,0);
    }

    // write acc -> outT (bf16): D frag: col = cc*16+(lane&15), row = m*16+(lane>>4)*4+r
    #pragma unroll
    for (int m=0;m<4;m++)
        #pragma unroll
        for (int i=0;i<3;i++)
            if (i < ncc){
                int col = ccl[i]*16 + (lane&15);
                #pragma unroll
                for (int r=0;r<4;r++){
                    int row = m*16 + (lane>>4)*4 + r;
                    outT[row*146 + col] = f2bf(acc[m][i][r]);
                }
            }
    __syncthreads();

    // softmax over n=32 for each of 16 (b,h) pairs; 16 threads per pair
    {
        int p = t >> 4, i = t & 15;
        int b = p >> 3, h = p & 7;
        float nsv = ns[(b0 + b)*8 + h];
        int row0 = b*32 + i, row1 = row0 + 16;
        float s0 = bf2f(outT[row0*146 + 128 + h]) + nsv;
        float s1 = bf2f(outT[row1*146 + 128 + h]) + nsv;
        s0 = s0 > 0.f ? s0 : 0.2f*s0;
        s1 = s1 > 0.f ? s1 : 0.2f*s1;
        float m = fmaxf(s0, s1);
        #pragma unroll
        for (int d=1; d<16; d<<=1) m = fmaxf(m, __shfl_xor(m, d));
        float e0 = __expf(s0 - m), e1 = __expf(s1 - m);
        float ssum = e0 + e1;
        #pragma unroll
        for (int d=1; d<16; d<<=1) ssum += __shfl_xor(ssum, d);
        float inv = 1.0f / ssum;
        cf[(b*32 + i)*8 + h]      = e0 * inv;
        cf[(b*32 + i + 16)*8 + h] = e1 * inv;
    }
    __syncthreads();

    // z[b][h][c] = sum_n coef[b][n][h] * neigh[b*32+n][c]
    {
        int b = t >> 7, c = t & 127;
        float az[8];
        #pragma unroll
        for (int h=0;h<8;h++) az[h]=0.f;
        for (int n=0;n<32;n++){
            float v = bf2f(outT[(b*32+n)*146 + c]);
            v4f c0 = *(const v4f*)&cf[(b*32+n)*8];
            v4f c1 = *(const v4f*)&cf[(b*32+n)*8 + 4];
            az[0] = fmaf(c0[0], v, az[0]); az[1] = fmaf(c0[1], v, az[1]);
            az[2] = fmaf(c0[2], v, az[2]); az[3] = fmaf(c0[3], v, az[3]);
            az[4] = fmaf(c1[0], v, az[4]); az[5] = fmaf(c1[1], v, az[5]);
            az[6] = fmaf(c1[2], v, az[6]); az[7] = fmaf(c1[3], v, az[7]);
        }
        size_t zb = ((size_t)(b0 + b)*3 + g)*1024;
        #pragma unroll
        for (int h=0;h<8;h++) zf[zb + h*128 + c] = az[h] + bias[h*128 + c];
    }
}

// ---------------- phase 2: sem scores s[b*3+g] ----------------
__global__ __launch_bounds__(256) void semk_kernel(const float* __restrict__ zf,
        const unsigned short* __restrict__ pack2, const float* __restrict__ sa,
        float* __restrict__ sws){
    __shared__ __align__(16) unsigned short aT[32*256];  // 16 KB
    __shared__ float sred[32*4];
    int t = threadIdx.x, w = t>>6, lane = t&63;
    int R0 = blockIdx.x * 32;
    v4f acc[2][2];
    #pragma unroll
    for (int m=0;m<2;m++)
        #pragma unroll
        for (int i=0;i<2;i++) acc[m][i] = (v4f){0.f,0.f,0.f,0.f};

    for (int kc=0;kc<4;kc++){
        #pragma unroll
        for (int i=0;i<8;i++){
            int fi = (i*256 + t)*4;
            int row = fi >> 8, d = fi & 255;
            v4f v = *(const v4f*)(zf + (size_t)(R0+row)*1024 + kc*256 + d);
            v4s h;
            h[0]=(short)f2bf(v[0]); h[1]=(short)f2bf(v[1]); h[2]=(short)f2bf(v[2]); h[3]=(short)f2bf(v[3]);
            int byte = row*512 + ((d*2) ^ ((row&7)<<4));
            *(v4s*)((char*)aT + byte) = h;
        }
        __syncthreads();
        for (int kk=0;kk<8;kk++){
            v8s bfr[2];
            #pragma unroll
            for (int i=0;i<2;i++){
                int cc = w + i*4;
                bfr[i] = *(const v8s*)(pack2 + ((((kc*8+kk)*8 + cc)*64 + lane) << 3));
            }
            v8s afr[2];
            #pragma unroll
            for (int m=0;m<2;m++){
                int row = m*16 + (lane&15);
                int d0  = kk*32 + (lane>>4)*8;
                int byte = row*512 + ((d0*2) ^ ((row&7)<<4));
                afr[m] = *(const v8s*)((const char*)aT + byte);
            }
            #pragma unroll
            for (int m=0;m<2;m++)
                #pragma unroll
                for (int i=0;i<2;i++)
                    acc[m][i] = __builtin_amdgcn_mfma_f32_16x16x32_bf16(afr[m], bfr[i], acc[m][i], 0,0,0);
        }
        __syncthreads();
    }
    // epilogue: s[row] = sum_col tanh(u[row][col]) * sa[col]
    #pragma unroll
    for (int m=0;m<2;m++)
        #pragma unroll
        for (int r=0;r<4;r++){
            float val = 0.f;
            #pragma unroll
            for (int i=0;i<2;i++){
                int col = (w + i*4)*16 + (lane&15);
                val = fmaf(tanhf(acc[m][i][r]), sa[col], val);
            }
            #pragma unroll
            for (int d=1; d<16; d<<=1) val += __shfl_xor(val, d);
            if ((lane&15)==0) sred[(m*16 + (lane>>4)*4 + r)*4 + w] = val;
        }
    __syncthreads();
    if (t < 32){
        float s = sred[t*4] + sred[t*4+1] + sred[t*4+2] + sred[t*4+3];
        sws[R0 + t] = s;
    }
}

// ---------------- phase 3: softmax over G, pool, dense ----------------
__global__ __launch_bounds__(256) void final_kernel(const float* __restrict__ zf,
        const float* __restrict__ sws, const float* __restrict__ dw,
        const float* __restrict__ db, float* __restrict__ outp){
    int tid = blockIdx.x*256 + threadIdx.x;   // 65536 = b*16 + l
    int b = tid >> 4, l = tid & 15;
    float s0 = sws[b*3], s1 = sws[b*3+1], s2 = sws[b*3+2];
    float m = fmaxf(s0, fmaxf(s1, s2));
    float e0 = __expf(s0-m), e1 = __expf(s1-m), e2 = __expf(s2-m);
    float inv = 1.0f/(e0+e1+e2);
    float a0 = e0*inv, a1 = e1*inv, a2 = e2*inv;
    const float* z0 = zf + (size_t)b*3072;
    float acc = 0.f;
    for (int c=0;c<1024;c++){
        float p = a0*z0[c] + a1*z0[1024+c] + a2*z0[2048+c];
        acc = fmaf(p, dw[c*16 + l], acc);
    }
    outp[tid] = acc + db[l];
}

extern "C" void kernel_launch(void* const* d_in, const int* in_sizes, int n_in,
                              void* d_out, int out_size, void* d_ws, size_t ws_size,
                              hipStream_t stream) {
    const float* targets  = (const float*)d_in[0];
    const float* contexts = (const float*)d_in[1];
    const float* kern     = (const float*)d_in[2];
    const float* ak       = (const float*)d_in[3];
    const float* bias     = (const float*)d_in[4];
    const float* semk     = (const float*)d_in[5];
    const float* sa       = (const float*)d_in[6];
    const float* dw       = (const float*)d_in[7];
    const float* db       = (const float*)d_in[8];
    float* outp = (float*)d_out;

    char* ws = (char*)d_ws;
    unsigned short* packB = (unsigned short*)(ws);             // 73728 B
    float* wn             = (float*)(ws + 73728);              // 8192 B
    float* wg             = (float*)(ws + 81920);              // 8192 B
    float* nsb            = (float*)(ws + 90112);              // 131072 B
    unsigned short* pack2 = (unsigned short*)(ws + 221184);    // 262144 B
    float* zf             = (float*)(ws + 483328);             // 50331648 B
    float* sws            = (float*)(ws + 50814976);           // 49152 B

    prep_a<<<1, 256, 0, stream>>>(kern, ak, wn, wg);
    prep_b<<<16, 256, 0, stream>>>(kern, wg, packB);
    prep_c<<<16, 256, 0, stream>>>(targets, wn, nsb);
    prep_d<<<32, 256, 0, stream>>>(semk, pack2);
    phase1<<<6144, 256, 0, stream>>>(contexts, packB, nsb, bias, zf);
    semk_kernel<<<384, 256, 0, stream>>>(zf, pack2, sa, sws);
    final_kernel<<<256, 256, 0, stream>>>(zf, sws, dw, db, outp);
}

// Round 2
// 227.466 us; speedup vs baseline: 1.3462x; 1.3462x over previous
//
#include <hip/hip_runtime.h>

typedef float v4f __attribute__((ext_vector_type(4)));
typedef short v8s __attribute__((ext_vector_type(8)));
typedef short v4s __attribute__((ext_vector_type(4)));

__device__ __forceinline__ unsigned short f2bf(float x){
    unsigned u = __float_as_uint(x);
    u += 0x7FFFu + ((u >> 16) & 1u);
    return (unsigned short)(u >> 16);
}
__device__ __forceinline__ float bf2f(unsigned short h){
    return __uint_as_float(((unsigned)h) << 16);
}

// ---------------- prep kernels ----------------
__global__ __launch_bounds__(256) void prep_a(const float* __restrict__ kern,
        const float* __restrict__ ak, float* __restrict__ wn, float* __restrict__ wg){
    int d = threadIdx.x;
    float an[8], ag[8];
    #pragma unroll
    for (int h=0;h<8;h++){ an[h]=0.f; ag[h]=0.f; }
    for (int c=0;c<128;c++){
        float kv = kern[d*128+c];
        #pragma unroll
        for (int h=0;h<8;h++){
            an[h] = fmaf(kv, ak[h*256+c], an[h]);
            ag[h] = fmaf(kv, ak[h*256+128+c], ag[h]);
        }
    }
    #pragma unroll
    for (int h=0;h<8;h++){ wn[d*8+h]=an[h]; wg[d*8+h]=ag[h]; }
}

// pack B = [kernel | W_neigh | 0pad] (256 x 144) into MFMA B-fragment order, bf16
__global__ __launch_bounds__(256) void prep_b(const float* __restrict__ kern,
        const float* __restrict__ wg, unsigned short* __restrict__ packB){
    int tid = blockIdx.x*256 + threadIdx.x;   // 4096 threads
    for (int r=0;r<9;r++){
        int e = tid + r*4096;                  // < 36864
        int j = e & 7; int rest = e >> 3;
        int l = rest & 63; rest >>= 6;
        int cc = rest % 9; int kk = rest / 9;
        int d = kk*32 + (l>>4)*8 + j;
        int c = cc*16 + (l&15);
        float v;
        if (cc < 8) v = kern[d*128 + c];
        else { int h = c - 128; v = (h < 8) ? wg[d*8+h] : 0.0f; }
        packB[e] = f2bf(v);
    }
}

// node_score[b][h] = targets[b] . W_node[:,h]  -- 8 independent accumulators
__global__ __launch_bounds__(256) void prep_c(const float* __restrict__ targ,
        const float* __restrict__ wn, float* __restrict__ ns){
    int b = blockIdx.x*256 + threadIdx.x;     // 4096
    float acc[8];
    #pragma unroll
    for (int h=0;h<8;h++) acc[h]=0.f;
    for (int d=0; d<256; d++){
        float tv = targ[b*256+d];
        #pragma unroll
        for (int h=0;h<8;h++) acc[h] = fmaf(tv, wn[d*8+h], acc[h]);
    }
    #pragma unroll
    for (int h=0;h<8;h++) ns[b*8+h] = acc[h];
}

// pack sem_kernel (1024 x 128) into MFMA B-fragment order, bf16
__global__ __launch_bounds__(256) void prep_d(const float* __restrict__ semk,
        unsigned short* __restrict__ pack2){
    int tid = blockIdx.x*256 + threadIdx.x;   // 8192
    for (int r=0;r<16;r++){
        int e = tid + r*8192;                  // 131072
        int j = e & 7; int rest = e >> 3;
        int l = rest & 63; rest >>= 6;
        int cc = rest & 7; rest >>= 3;
        int kk = rest & 7; int kc = rest >> 3;
        int k = kc*256 + kk*32 + (l>>4)*8 + j;
        int a = cc*16 + (l&15);
        pack2[e] = f2bf(semk[k*128 + a]);
    }
}

// ---------------- phase 1: fused neigh GEMM + scores + softmax + z ----------------
__global__ __launch_bounds__(256) void phase1(const float* __restrict__ ctx,
        const unsigned short* __restrict__ packB, const float* __restrict__ ns,
        const float* __restrict__ bias, unsigned short* __restrict__ zb16){
    __shared__ __align__(16) unsigned short aT[64*256];    // 32 KB, xor-swizzled bf16
    __shared__ __align__(16) unsigned short outT[64*146];  // 18.25 KB bf16 (neigh+scores)
    __shared__ float cf[2*32*8];                           // coef [b][n][h], 2 KB

    int t = threadIdx.x;
    int bid = blockIdx.x;          // 6144 = 3 * 2048
    int g  = bid >> 11;
    int b0 = (bid & 2047) * 2;
    const float* cbase = ctx + (size_t)(g*4096 + b0) * 8192;

    int w = t >> 6, lane = t & 63;
    int ncc = (w==0) ? 3 : 2;
    int ccl[3] = {w, w+4, 8};
    v4f acc[4][3];
    #pragma unroll
    for (int m=0;m<4;m++)
        #pragma unroll
        for (int i=0;i<3;i++) acc[m][i] = (v4f){0.f,0.f,0.f,0.f};

    int srow = t >> 5;          // 0..7
    int sd   = (t & 31) * 4;    // 0..124

    // ---- stage K-half 0 (d < 128) ----
    v4f pf[8];
    #pragma unroll
    for (int i=0;i<8;i++)
        pf[i] = *(const v4f*)(cbase + (i*8 + srow)*256 + sd);
    #pragma unroll
    for (int i=0;i<8;i++){
        int row = i*8 + srow;
        v4s h;
        h[0]=(short)f2bf(pf[i][0]); h[1]=(short)f2bf(pf[i][1]);
        h[2]=(short)f2bf(pf[i][2]); h[3]=(short)f2bf(pf[i][3]);
        int byte = row*512 + ((sd*2) ^ ((row&7)<<4));
        *(v4s*)((char*)aT + byte) = h;
    }
    __syncthreads();

    // ---- prefetch K-half 1 (d >= 128) into regs ----
    #pragma unroll
    for (int i=0;i<8;i++)
        pf[i] = *(const v4f*)(cbase + (i*8 + srow)*256 + 128 + sd);

    // ---- MFMA on K-half 0 ----
    #pragma unroll
    for (int kk=0;kk<4;kk++){
        v8s bfr[3];
        #pragma unroll
        for (int i=0;i<3;i++)
            if (i < ncc)
                bfr[i] = *(const v8s*)(packB + (((kk*9 + ccl[i])*64 + lane) << 3));
        v8s afr[4];
        #pragma unroll
        for (int m=0;m<4;m++){
            int row = m*16 + (lane&15);
            int d0  = kk*32 + (lane>>4)*8;
            int byte = row*512 + ((d0*2) ^ ((row&7)<<4));
            afr[m] = *(const v8s*)((const char*)aT + byte);
        }
        #pragma unroll
        for (int m=0;m<4;m++)
            #pragma unroll
            for (int i=0;i<3;i++)
                if (i < ncc)
                    acc[m][i] = __builtin_amdgcn_mfma_f32_16x16x32_bf16(afr[m], bfr[i], acc[m][i], 0,0,0);
    }

    // ---- write K-half 1 to LDS ----
    #pragma unroll
    for (int i=0;i<8;i++){
        int row = i*8 + srow;
        int d = 128 + sd;
        v4s h;
        h[0]=(short)f2bf(pf[i][0]); h[1]=(short)f2bf(pf[i][1]);
        h[2]=(short)f2bf(pf[i][2]); h[3]=(short)f2bf(pf[i][3]);
        int byte = row*512 + ((d*2) ^ ((row&7)<<4));
        *(v4s*)((char*)aT + byte) = h;
    }
    __syncthreads();

    // ---- MFMA on K-half 1 ----
    #pragma unroll
    for (int kk=4;kk<8;kk++){
        v8s bfr[3];
        #pragma unroll
        for (int i=0;i<3;i++)
            if (i < ncc)
                bfr[i] = *(const v8s*)(packB + (((kk*9 + ccl[i])*64 + lane) << 3));
        v8s afr[4];
        #pragma unroll
        for (int m=0;m<4;m++){
            int row = m*16 + (lane&15);
            int d0  = kk*32 + (lane>>4)*8;
            int byte = row*512 + ((d0*2) ^ ((row&7)<<4));
            afr[m] = *(const v8s*)((const char*)aT + byte);
        }
        #pragma unroll
        for (int m=0;m<4;m++)
            #pragma unroll
            for (int i=0;i<3;i++)
                if (i < ncc)
                    acc[m][i] = __builtin_amdgcn_mfma_f32_16x16x32_bf16(afr[m], bfr[i], acc[m][i], 0,0,0);
    }

    // write acc -> outT (bf16)
    #pragma unroll
    for (int m=0;m<4;m++)
        #pragma unroll
        for (int i=0;i<3;i++)
            if (i < ncc){
                int col = ccl[i]*16 + (lane&15);
                #pragma unroll
                for (int r=0;r<4;r++){
                    int row = m*16 + (lane>>4)*4 + r;
                    outT[row*146 + col] = f2bf(acc[m][i][r]);
                }
            }
    __syncthreads();

    // softmax over n=32 for each of 16 (b,h) pairs; 16 threads per pair
    {
        int p = t >> 4, i = t & 15;
        int b = p >> 3, h = p & 7;
        float nsv = ns[(b0 + b)*8 + h];
        int row0 = b*32 + i, row1 = row0 + 16;
        float s0 = bf2f(outT[row0*146 + 128 + h]) + nsv;
        float s1 = bf2f(outT[row1*146 + 128 + h]) + nsv;
        s0 = s0 > 0.f ? s0 : 0.2f*s0;
        s1 = s1 > 0.f ? s1 : 0.2f*s1;
        float m = fmaxf(s0, s1);
        #pragma unroll
        for (int d=1; d<16; d<<=1) m = fmaxf(m, __shfl_xor(m, d));
        float e0 = __expf(s0 - m), e1 = __expf(s1 - m);
        float ssum = e0 + e1;
        #pragma unroll
        for (int d=1; d<16; d<<=1) ssum += __shfl_xor(ssum, d);
        float inv = 1.0f / ssum;
        cf[(b*32 + i)*8 + h]      = e0 * inv;
        cf[(b*32 + i + 16)*8 + h] = e1 * inv;
    }
    __syncthreads();

    // z[b][h][c] = sum_n coef[b][n][h] * neigh[b*32+n][c]  -> bf16
    {
        int b = t >> 7, c = t & 127;
        float az[8];
        #pragma unroll
        for (int h=0;h<8;h++) az[h]=0.f;
        for (int n=0;n<32;n++){
            float v = bf2f(outT[(b*32+n)*146 + c]);
            v4f c0 = *(const v4f*)&cf[(b*32+n)*8];
            v4f c1 = *(const v4f*)&cf[(b*32+n)*8 + 4];
            az[0] = fmaf(c0[0], v, az[0]); az[1] = fmaf(c0[1], v, az[1]);
            az[2] = fmaf(c0[2], v, az[2]); az[3] = fmaf(c0[3], v, az[3]);
            az[4] = fmaf(c1[0], v, az[4]); az[5] = fmaf(c1[1], v, az[5]);
            az[6] = fmaf(c1[2], v, az[6]); az[7] = fmaf(c1[3], v, az[7]);
        }
        size_t zb = ((size_t)(b0 + b)*3 + g)*1024;
        #pragma unroll
        for (int h=0;h<8;h++) zb16[zb + h*128 + c] = f2bf(az[h] + bias[h*128 + c]);
    }
}

// ---------------- phase 2: sem scores, LDS-free, A direct from bf16 zf ----------------
__global__ __launch_bounds__(256) void semk2(const unsigned short* __restrict__ zb16,
        const unsigned short* __restrict__ pack2, const float* __restrict__ sa,
        float* __restrict__ sws){
    __shared__ float red[16*4];
    int t = threadIdx.x, w = t>>6, lane = t&63;
    int r0 = blockIdx.x * 16;   // 768 blocks, 16 rows each
    v4f acc0 = (v4f){0.f,0.f,0.f,0.f};
    v4f acc1 = (v4f){0.f,0.f,0.f,0.f};
    const unsigned short* abase = zb16 + (size_t)(r0 + (lane&15))*1024 + (lane>>4)*8;
    #pragma unroll 4
    for (int kk=0; kk<32; kk++){
        v8s afr = *(const v8s*)(abase + kk*32);
        v8s b0  = *(const v8s*)(pack2 + (((kk*8 + w  )*64 + lane) << 3));
        v8s b1  = *(const v8s*)(pack2 + (((kk*8 + w+4)*64 + lane) << 3));
        acc0 = __builtin_amdgcn_mfma_f32_16x16x32_bf16(afr, b0, acc0, 0,0,0);
        acc1 = __builtin_amdgcn_mfma_f32_16x16x32_bf16(afr, b1, acc1, 0,0,0);
    }
    float sa0 = sa[w*16 + (lane&15)];
    float sa1 = sa[(w+4)*16 + (lane&15)];
    #pragma unroll
    for (int r=0;r<4;r++){
        float v = fmaf(tanhf(acc0[r]), sa0, tanhf(acc1[r]) * sa1);
        #pragma unroll
        for (int d=1; d<16; d<<=1) v += __shfl_xor(v, d);
        if ((lane&15)==0) red[((lane>>4)*4 + r)*4 + w] = v;
    }
    __syncthreads();
    if (t < 16)
        sws[r0 + t] = red[t*4] + red[t*4+1] + red[t*4+2] + red[t*4+3];
}

// ---------------- phase 3: softmax over G, pool, dense ----------------
__global__ __launch_bounds__(64) void final3(const unsigned short* __restrict__ zb16,
        const float* __restrict__ sws, const float* __restrict__ dw,
        const float* __restrict__ db, float* __restrict__ outp){
    int b = blockIdx.x;        // 4096
    int lane = threadIdx.x;    // 64
    float s0 = sws[b*3], s1 = sws[b*3+1], s2 = sws[b*3+2];
    float m = fmaxf(s0, fmaxf(s1, s2));
    float e0 = __expf(s0-m), e1 = __expf(s1-m), e2 = __expf(s2-m);
    float inv = 1.0f/(e0+e1+e2);
    float a0 = e0*inv, a1 = e1*inv, a2 = e2*inv;

    const unsigned short* z0 = zb16 + (size_t)b*3072 + lane*16;
    v8s za0 = *(const v8s*)(z0);          v8s za1 = *(const v8s*)(z0+8);
    v8s zb0 = *(const v8s*)(z0+1024);     v8s zb1 = *(const v8s*)(z0+1032);
    v8s zc0 = *(const v8s*)(z0+2048);     v8s zc1 = *(const v8s*)(z0+2056);
    float p[16];
    #pragma unroll
    for (int k=0;k<8;k++){
        p[k]   = a0*bf2f((unsigned short)za0[k]) + a1*bf2f((unsigned short)zb0[k]) + a2*bf2f((unsigned short)zc0[k]);
        p[k+8] = a0*bf2f((unsigned short)za1[k]) + a1*bf2f((unsigned short)zb1[k]) + a2*bf2f((unsigned short)zc1[k]);
    }
    float acc[16];
    #pragma unroll
    for (int l=0;l<16;l++) acc[l]=0.f;
    #pragma unroll
    for (int k=0;k<16;k++){
        const float* dr = dw + (lane*16 + k)*16;
        v4f d0 = *(const v4f*)(dr);
        v4f d1 = *(const v4f*)(dr+4);
        v4f d2 = *(const v4f*)(dr+8);
        v4f d3 = *(const v4f*)(dr+12);
        float pk = p[k];
        acc[0]=fmaf(pk,d0[0],acc[0]);  acc[1]=fmaf(pk,d0[1],acc[1]);
        acc[2]=fmaf(pk,d0[2],acc[2]);  acc[3]=fmaf(pk,d0[3],acc[3]);
        acc[4]=fmaf(pk,d1[0],acc[4]);  acc[5]=fmaf(pk,d1[1],acc[5]);
        acc[6]=fmaf(pk,d1[2],acc[6]);  acc[7]=fmaf(pk,d1[3],acc[7]);
        acc[8]=fmaf(pk,d2[0],acc[8]);  acc[9]=fmaf(pk,d2[1],acc[9]);
        acc[10]=fmaf(pk,d2[2],acc[10]); acc[11]=fmaf(pk,d2[3],acc[11]);
        acc[12]=fmaf(pk,d3[0],acc[12]); acc[13]=fmaf(pk,d3[1],acc[13]);
        acc[14]=fmaf(pk,d3[2],acc[14]); acc[15]=fmaf(pk,d3[3],acc[15]);
    }
    #pragma unroll
    for (int l=0;l<16;l++){
        float v = acc[l];
        #pragma unroll
        for (int d=1; d<64; d<<=1) v += __shfl_xor(v, d);
        acc[l] = v;
    }
    float myv = 0.f;
    #pragma unroll
    for (int l=0;l<16;l++) myv = (lane==l) ? acc[l] : myv;
    if (lane < 16) outp[b*16 + lane] = myv + db[lane];
}

extern "C" void kernel_launch(void* const* d_in, const int* in_sizes, int n_in,
                              void* d_out, int out_size, void* d_ws, size_t ws_size,
                              hipStream_t stream) {
    const float* targets  = (const float*)d_in[0];
    const float* contexts = (const float*)d_in[1];
    const float* kern     = (const float*)d_in[2];
    const float* ak       = (const float*)d_in[3];
    const float* bias     = (const float*)d_in[4];
    const float* semk     = (const float*)d_in[5];
    const float* sa       = (const float*)d_in[6];
    const float* dw       = (const float*)d_in[7];
    const float* db       = (const float*)d_in[8];
    float* outp = (float*)d_out;

    char* ws = (char*)d_ws;
    unsigned short* packB = (unsigned short*)(ws);             // 73728 B
    float* wn             = (float*)(ws + 73728);              // 8192 B
    float* wg             = (float*)(ws + 81920);              // 8192 B
    float* nsb            = (float*)(ws + 90112);              // 131072 B
    unsigned short* pack2 = (unsigned short*)(ws + 221184);    // 262144 B
    unsigned short* zb16  = (unsigned short*)(ws + 483328);    // 25165824 B
    float* sws            = (float*)(ws + 25649152);           // 49152 B

    prep_a<<<1, 256, 0, stream>>>(kern, ak, wn, wg);
    prep_b<<<16, 256, 0, stream>>>(kern, wg, packB);
    prep_c<<<16, 256, 0, stream>>>(targets, wn, nsb);
    prep_d<<<32, 256, 0, stream>>>(semk, pack2);
    phase1<<<6144, 256, 0, stream>>>(contexts, packB, nsb, bias, zb16);
    semk2<<<768, 256, 0, stream>>>(zb16, pack2, sa, sws);
    final3<<<4096, 64, 0, stream>>>(zb16, sws, dw, db, outp);
}

// Round 3
// 218.919 us; speedup vs baseline: 1.3987x; 1.0390x over previous
//
#include <hip/hip_runtime.h>
#include <hip/hip_bf16.h>

typedef float v4f __attribute__((ext_vector_type(4)));
typedef short v8s __attribute__((ext_vector_type(8)));

__device__ __forceinline__ unsigned short f2bf(float x){
    unsigned u = __float_as_uint(x);
    u += 0x7FFFu + ((u >> 16) & 1u);
    return (unsigned short)(u >> 16);
}
__device__ __forceinline__ float bf2f(unsigned short h){
    return __uint_as_float(((unsigned)h) << 16);
}
__device__ __forceinline__ v8s pack_bf8(v4f a, v4f b){
    union { v8s s; __hip_bfloat162 h[4]; } u;
    u.h[0] = __float22bfloat162_rn(float2{a[0],a[1]});
    u.h[1] = __float22bfloat162_rn(float2{a[2],a[3]});
    u.h[2] = __float22bfloat162_rn(float2{b[0],b[1]});
    u.h[3] = __float22bfloat162_rn(float2{b[2],b[3]});
    return u.s;
}

// ---------------- merged prep kernel ----------------
// blocks 0-15 : ns[b][h]  (recompute W_node in LDS, then targets @ W_node)
// blocks 16-17: packB     (recompute W_neigh in LDS, pack [kernel|W_neigh|0])
// blocks 18-49: pack2     (pack sem_kernel into B-fragment order)
__global__ __launch_bounds__(256) void prep_all(const float* __restrict__ targ,
        const float* __restrict__ kern, const float* __restrict__ ak,
        const float* __restrict__ semk, float* __restrict__ ns,
        unsigned short* __restrict__ packB, unsigned short* __restrict__ pack2){
    __shared__ float wsh[256*8];
    int blk = blockIdx.x, t = threadIdx.x;
    if (blk < 16){
        {   // W_node[d][h], d = t
            float a[8];
            #pragma unroll
            for (int h=0;h<8;h++) a[h]=0.f;
            const float* kr = kern + t*128;
            for (int c=0;c<128;c++){
                float kv = kr[c];
                #pragma unroll
                for (int h=0;h<8;h++) a[h] = fmaf(kv, ak[h*256+c], a[h]);
            }
            #pragma unroll
            for (int h=0;h<8;h++) wsh[t*8+h]=a[h];
        }
        __syncthreads();
        int b = blk*256 + t;
        float acc[8];
        #pragma unroll
        for (int h=0;h<8;h++) acc[h]=0.f;
        const float* tr = targ + (size_t)b*256;
        for (int d=0;d<256;d++){
            float tv = tr[d];
            #pragma unroll
            for (int h=0;h<8;h++) acc[h] = fmaf(tv, wsh[d*8+h], acc[h]);
        }
        #pragma unroll
        for (int h=0;h<8;h++) ns[b*8+h]=acc[h];
    } else if (blk < 18){
        {   // W_neigh[d][h], d = t
            float a[8];
            #pragma unroll
            for (int h=0;h<8;h++) a[h]=0.f;
            const float* kr = kern + t*128;
            for (int c=0;c<128;c++){
                float kv = kr[c];
                #pragma unroll
                for (int h=0;h<8;h++) a[h] = fmaf(kv, ak[h*256+128+c], a[h]);
            }
            #pragma unroll
            for (int h=0;h<8;h++) wsh[t*8+h]=a[h];
        }
        __syncthreads();
        int gt = (blk-16)*256 + t;            // 0..511
        for (int r=0;r<72;r++){
            int e = gt + r*512;                // < 36864
            int j = e & 7; int l = (e>>3) & 63;
            int fc = e >> 9; int cc = fc % 9; int kk = fc / 9;
            int d = kk*32 + (l>>4)*8 + j;
            int c = cc*16 + (l&15);
            float v;
            if (cc < 8) v = kern[d*128 + c];
            else { int h = c - 128; v = (h < 8) ? wsh[d*8+h] : 0.0f; }
            packB[e] = f2bf(v);
        }
    } else {
        int gt = (blk-18)*256 + t;            // 0..8191
        for (int r=0;r<16;r++){
            int e = gt + r*8192;               // < 131072
            int j = e & 7; int l = (e>>3) & 63;
            int cc = (e>>9) & 7; int gkk = e >> 12;   // 0..31
            int k = gkk*32 + (l>>4)*8 + j;
            int a2 = cc*16 + (l&15);
            pack2[e] = f2bf(semk[k*128 + a2]);
        }
    }
}

// ---------------- phase 1: LDS-free A, fused GEMM + scores + softmax + z ----------------
// block = (g, 2 b's) = 64 rows. wave w owns m-tile rows w*16..w*16+15, all 9 cc tiles.
__global__ __launch_bounds__(256,4) void phase1(const float* __restrict__ ctx,
        const unsigned short* __restrict__ packB, const float* __restrict__ ns,
        const float* __restrict__ bias, unsigned short* __restrict__ zb16){
    __shared__ __align__(16) unsigned short outT[64*146];  // 18.25 KB (neigh | scores)
    __shared__ float cf[2*32*8];                           // coef, 2 KB

    int t = threadIdx.x;
    int bid = blockIdx.x;          // 6144 = 3 * 2048
    int g  = bid >> 11;
    int b0 = (bid & 2047) * 2;
    int w = t >> 6, lane = t & 63;

    const float* abase = ctx + (size_t)((g*4096 + b0)*32 + w*16 + (lane&15))*256 + ((lane>>4)*8);
    const unsigned short* bbase = packB + lane*8;

    v4f acc[9];
    #pragma unroll
    for (int i=0;i<9;i++) acc[i] = (v4f){0.f,0.f,0.f,0.f};

    #pragma unroll
    for (int kk=0;kk<8;kk++){
        v4f a0 = *(const v4f*)(abase + kk*32);
        v4f a1 = *(const v4f*)(abase + kk*32 + 4);
        v8s afr = pack_bf8(a0, a1);
        #pragma unroll
        for (int cc=0;cc<9;cc++){
            v8s bfr = *(const v8s*)(bbase + (kk*9+cc)*512);
            acc[cc] = __builtin_amdgcn_mfma_f32_16x16x32_bf16(afr, bfr, acc[cc], 0,0,0);
        }
    }

    // write acc -> outT (bf16): row = w*16+(lane>>4)*4+r, col = cc*16+(lane&15)
    int qr = (lane>>4)*4;
    #pragma unroll
    for (int cc=0;cc<9;cc++){
        int col = cc*16 + (lane&15);
        #pragma unroll
        for (int r=0;r<4;r++)
            outT[(w*16 + qr + r)*146 + col] = f2bf(acc[cc][r]);
    }
    __syncthreads();

    // softmax over n=32 for each of 16 (b,h) pairs; 16 threads per pair
    {
        int p = t >> 4, i = t & 15;
        int b = p >> 3, h = p & 7;
        float nsv = ns[(b0 + b)*8 + h];
        int row0 = b*32 + i, row1 = row0 + 16;
        float s0 = bf2f(outT[row0*146 + 128 + h]) + nsv;
        float s1 = bf2f(outT[row1*146 + 128 + h]) + nsv;
        s0 = s0 > 0.f ? s0 : 0.2f*s0;
        s1 = s1 > 0.f ? s1 : 0.2f*s1;
        float m = fmaxf(s0, s1);
        #pragma unroll
        for (int d=1; d<16; d<<=1) m = fmaxf(m, __shfl_xor(m, d));
        float e0 = __expf(s0 - m), e1 = __expf(s1 - m);
        float ssum = e0 + e1;
        #pragma unroll
        for (int d=1; d<16; d<<=1) ssum += __shfl_xor(ssum, d);
        float inv = 1.0f / ssum;
        cf[(b*32 + i)*8 + h]      = e0 * inv;
        cf[(b*32 + i + 16)*8 + h] = e1 * inv;
    }
    __syncthreads();

    // z[b][h][c] = sum_n coef[b][n][h] * neigh[b*32+n][c]  -> bf16
    {
        int b = t >> 7, c = t & 127;
        float az[8];
        #pragma unroll
        for (int h=0;h<8;h++) az[h]=0.f;
        for (int n=0;n<32;n++){
            float v = bf2f(outT[(b*32+n)*146 + c]);
            v4f c0 = *(const v4f*)&cf[(b*32+n)*8];
            v4f c1 = *(const v4f*)&cf[(b*32+n)*8 + 4];
            az[0] = fmaf(c0[0], v, az[0]); az[1] = fmaf(c0[1], v, az[1]);
            az[2] = fmaf(c0[2], v, az[2]); az[3] = fmaf(c0[3], v, az[3]);
            az[4] = fmaf(c1[0], v, az[4]); az[5] = fmaf(c1[1], v, az[5]);
            az[6] = fmaf(c1[2], v, az[6]); az[7] = fmaf(c1[3], v, az[7]);
        }
        size_t zb = ((size_t)(b0 + b)*3 + g)*1024;
        #pragma unroll
        for (int h=0;h<8;h++) zb16[zb + h*128 + c] = f2bf(az[h] + bias[h*128 + c]);
    }
}

// ---------------- phase 2: sem scores, LDS-free, A direct from bf16 zf ----------------
__global__ __launch_bounds__(256) void semk2(const unsigned short* __restrict__ zb16,
        const unsigned short* __restrict__ pack2, const float* __restrict__ sa,
        float* __restrict__ sws){
    __shared__ float red[16*4];
    int t = threadIdx.x, w = t>>6, lane = t&63;
    int r0 = blockIdx.x * 16;   // 768 blocks, 16 rows each
    v4f acc0 = (v4f){0.f,0.f,0.f,0.f};
    v4f acc1 = (v4f){0.f,0.f,0.f,0.f};
    const unsigned short* abase = zb16 + (size_t)(r0 + (lane&15))*1024 + (lane>>4)*8;
    #pragma unroll 4
    for (int kk=0; kk<32; kk++){
        v8s afr = *(const v8s*)(abase + kk*32);
        v8s b0  = *(const v8s*)(pack2 + (((kk*8 + w  )*64 + lane) << 3));
        v8s b1  = *(const v8s*)(pack2 + (((kk*8 + w+4)*64 + lane) << 3));
        acc0 = __builtin_amdgcn_mfma_f32_16x16x32_bf16(afr, b0, acc0, 0,0,0);
        acc1 = __builtin_amdgcn_mfma_f32_16x16x32_bf16(afr, b1, acc1, 0,0,0);
    }
    float sa0 = sa[w*16 + (lane&15)];
    float sa1 = sa[(w+4)*16 + (lane&15)];
    #pragma unroll
    for (int r=0;r<4;r++){
        float v = fmaf(tanhf(acc0[r]), sa0, tanhf(acc1[r]) * sa1);
        #pragma unroll
        for (int d=1; d<16; d<<=1) v += __shfl_xor(v, d);
        if ((lane&15)==0) red[((lane>>4)*4 + r)*4 + w] = v;
    }
    __syncthreads();
    if (t < 16)
        sws[r0 + t] = red[t*4] + red[t*4+1] + red[t*4+2] + red[t*4+3];
}

// ---------------- phase 3: softmax over G, pool, dense ----------------
__global__ __launch_bounds__(64) void final3(const unsigned short* __restrict__ zb16,
        const float* __restrict__ sws, const float* __restrict__ dw,
        const float* __restrict__ db, float* __restrict__ outp){
    int b = blockIdx.x;        // 4096
    int lane = threadIdx.x;    // 64
    float s0 = sws[b*3], s1 = sws[b*3+1], s2 = sws[b*3+2];
    float m = fmaxf(s0, fmaxf(s1, s2));
    float e0 = __expf(s0-m), e1 = __expf(s1-m), e2 = __expf(s2-m);
    float inv = 1.0f/(e0+e1+e2);
    float a0 = e0*inv, a1 = e1*inv, a2 = e2*inv;

    const unsigned short* z0 = zb16 + (size_t)b*3072 + lane*16;
    v8s za0 = *(const v8s*)(z0);          v8s za1 = *(const v8s*)(z0+8);
    v8s zb0 = *(const v8s*)(z0+1024);     v8s zb1 = *(const v8s*)(z0+1032);
    v8s zc0 = *(const v8s*)(z0+2048);     v8s zc1 = *(const v8s*)(z0+2056);
    float p[16];
    #pragma unroll
    for (int k=0;k<8;k++){
        p[k]   = a0*bf2f((unsigned short)za0[k]) + a1*bf2f((unsigned short)zb0[k]) + a2*bf2f((unsigned short)zc0[k]);
        p[k+8] = a0*bf2f((unsigned short)za1[k]) + a1*bf2f((unsigned short)zb1[k]) + a2*bf2f((unsigned short)zc1[k]);
    }
    float acc[16];
    #pragma unroll
    for (int l=0;l<16;l++) acc[l]=0.f;
    #pragma unroll
    for (int k=0;k<16;k++){
        const float* dr = dw + (lane*16 + k)*16;
        v4f d0 = *(const v4f*)(dr);
        v4f d1 = *(const v4f*)(dr+4);
        v4f d2 = *(const v4f*)(dr+8);
        v4f d3 = *(const v4f*)(dr+12);
        float pk = p[k];
        acc[0]=fmaf(pk,d0[0],acc[0]);  acc[1]=fmaf(pk,d0[1],acc[1]);
        acc[2]=fmaf(pk,d0[2],acc[2]);  acc[3]=fmaf(pk,d0[3],acc[3]);
        acc[4]=fmaf(pk,d1[0],acc[4]);  acc[5]=fmaf(pk,d1[1],acc[5]);
        acc[6]=fmaf(pk,d1[2],acc[6]);  acc[7]=fmaf(pk,d1[3],acc[7]);
        acc[8]=fmaf(pk,d2[0],acc[8]);  acc[9]=fmaf(pk,d2[1],acc[9]);
        acc[10]=fmaf(pk,d2[2],acc[10]); acc[11]=fmaf(pk,d2[3],acc[11]);
        acc[12]=fmaf(pk,d3[0],acc[12]); acc[13]=fmaf(pk,d3[1],acc[13]);
        acc[14]=fmaf(pk,d3[2],acc[14]); acc[15]=fmaf(pk,d3[3],acc[15]);
    }
    #pragma unroll
    for (int l=0;l<16;l++){
        float v = acc[l];
        #pragma unroll
        for (int d=1; d<64; d<<=1) v += __shfl_xor(v, d);
        acc[l] = v;
    }
    float myv = 0.f;
    #pragma unroll
    for (int l=0;l<16;l++) myv = (lane==l) ? acc[l] : myv;
    if (lane < 16) outp[b*16 + lane] = myv + db[lane];
}

extern "C" void kernel_launch(void* const* d_in, const int* in_sizes, int n_in,
                              void* d_out, int out_size, void* d_ws, size_t ws_size,
                              hipStream_t stream) {
    const float* targets  = (const float*)d_in[0];
    const float* contexts = (const float*)d_in[1];
    const float* kern     = (const float*)d_in[2];
    const float* ak       = (const float*)d_in[3];
    const float* bias     = (const float*)d_in[4];
    const float* semk     = (const float*)d_in[5];
    const float* sa       = (const float*)d_in[6];
    const float* dw       = (const float*)d_in[7];
    const float* db       = (const float*)d_in[8];
    float* outp = (float*)d_out;

    char* ws = (char*)d_ws;
    unsigned short* packB = (unsigned short*)(ws);             // 73728 B
    float* nsb            = (float*)(ws + 73728);              // 131072 B
    unsigned short* pack2 = (unsigned short*)(ws + 204800);    // 262144 B
    unsigned short* zb16  = (unsigned short*)(ws + 466944);    // 25165824 B
    float* sws            = (float*)(ws + 25632768);           // 49152 B

    prep_all<<<50, 256, 0, stream>>>(targets, kern, ak, semk, nsb, packB, pack2);
    phase1<<<6144, 256, 0, stream>>>(contexts, packB, nsb, bias, zb16);
    semk2<<<768, 256, 0, stream>>>(zb16, pack2, sa, sws);
    final3<<<4096, 64, 0, stream>>>(zb16, sws, dw, db, outp);
}